// Round 16
// baseline (105.382 us; speedup 1.0000x reference)
//
#include <hip/hip_runtime.h>

#define NPTS 65536
#define V 4096
#define C 32
#define HH 64
#define WW 64
#define NSPLIT 4
#define MARG 2.0e-3f

typedef short bf8 __attribute__((ext_vector_type(8)));   // 8 bf16 in 4 VGPRs
typedef float f4 __attribute__((ext_vector_type(4)));

__device__ inline unsigned int ford(float d) {
    unsigned int b = __float_as_uint(d);
    return (b & 0x80000000u) ? ~b : (b | 0x80000000u);
}
__device__ inline short bf16rne(float x) {
    unsigned u = __float_as_uint(x);
    unsigned hb = (u + 0x7FFFu + ((u >> 16) & 1u)) & 0xFFFF0000u;
    return (short)(hb >> 16);
}
__device__ inline float bf16rne_f(float x, short* s) {
    unsigned u = __float_as_uint(x);
    unsigned hb = (u + 0x7FFFu + ((u >> 16) & 1u)) & 0xFFFF0000u;
    *s = (short)(hb >> 16);
    return __uint_as_float(hb);
}
// pack: (bits(a) & ~63) | vtb  -- compiler emits v_and_or_b32
__device__ inline float packkey(float a, unsigned vtb) {
    return __uint_as_float((__float_as_uint(a) & 0xFFFFFFC0u) | vtb);
}

// ---- fused prep, flat work items, 402 x 64 threads ----
__global__ void k_prep(const float* __restrict__ emb, const float* __restrict__ cw,
                       float* __restrict__ enneg, unsigned short* __restrict__ EB16,
                       bf8* __restrict__ EH, bf8* __restrict__ EL,
                       bf8* __restrict__ WB, int* __restrict__ cnt) {
    int g = blockIdx.x * 64 + threadIdx.x;
    if (g < 16384) {                      // codebook -> bf16 hi/lo fragments
        int vt = g >> 6, lane = g & 63;
        int col = lane & 15, k0 = (lane >> 4) * 8;
        const float* e = emb + (vt * 16 + col) * C + k0;
        bf8 h, l;
#pragma unroll
        for (int j = 0; j < 8; ++j) {
            short hs;
            float hf = bf16rne_f(e[j], &hs);
            h[j] = hs;
            l[j] = bf16rne(e[j] - hf);
        }
        EH[g] = h;
        EL[g] = l;
    } else if (g < 20480) {               // enneg = -0.5*||e||^2
        if (g == 16384) { cnt[0] = 0; cnt[1] = 0; }
        int v = g - 16384;
        const float4* e4 = (const float4*)(emb + v * C);
        float s = 0.f;
#pragma unroll
        for (int j = 0; j < 8; ++j) {
            float4 q = e4[j];
            s += q.x*q.x + q.y*q.y + q.z*q.z + q.w*q.w;
        }
        enneg[v] = -0.5f * s;
    } else if (g < 24576) {               // EB16: codebook rows in bf16
        int v = g - 20480;
        const float* e = emb + v * C;
        union { unsigned short us[32]; int4 q[4]; } u;
#pragma unroll
        for (int j = 0; j < 32; ++j) u.us[j] = (unsigned short)bf16rne(e[j]);
        int4* dst = (int4*)(EB16 + v * 32);
#pragma unroll
        for (int j = 0; j < 4; ++j) dst[j] = u.q[j];
    } else if (g < 25728) {               // WB: conv weights as MFMA B-fragments
        int e = g - 24576;
        int tap = e >> 7, rem = e & 127, half = rem >> 6, lane = rem & 63;
        int oc = half * 16 + (lane & 15), k0 = (lane >> 4) * 8;
        bf8 w;
#pragma unroll
        for (int j = 0; j < 8; ++j)
            w[j] = bf16rne(cw[oc * 288 + (k0 + j) * 9 + tap]);
        WB[e] = w;
    }
}

// ---- MFMA coarse argmin: 32 pts/wave, 1024 codes/split, 2048 blocks ----
// (256,6): VGPR cap 85 > the ~60 used -> no spill; up to 6 blocks/CU resident
__global__ __launch_bounds__(256, 6) void k_argmfma(const float* __restrict__ f,
        const bf8* __restrict__ EH, const bf8* __restrict__ EL,
        const float* __restrict__ enneg, float* __restrict__ bvv,
        float* __restrict__ b2a, int* __restrict__ iva) {
    __shared__ bf8 sEH[512];
    __shared__ bf8 sEL[512];
    __shared__ float sen[128];

    int tid = threadIdx.x;
    int lane = tid & 63;
    int wv = tid >> 6;
    int ci = blockIdx.x >> 9;
    int pb = blockIdx.x & 511;
    int base = pb * 128 + wv * 32;
    int col = lane & 15, kb = lane >> 4;

    bf8 xh[2], xl[2];
#pragma unroll
    for (int t = 0; t < 2; ++t) {
        int n = base + t * 16 + col;
        int b = n >> 12, pix = n & 4095;
        const float* fp = f + ((size_t)(b * C + kb * 8)) * 4096 + pix;
#pragma unroll
        for (int j = 0; j < 8; ++j) {
            float x = fp[(size_t)j * 4096];
            short hs;
            float hf = bf16rne_f(x, &hs);
            xh[t][j] = hs;
            xl[t][j] = bf16rne(x - hf);
        }
    }

    float best[8], best2[8];
#pragma unroll
    for (int e = 0; e < 8; ++e) { best[e] = -3.4e38f; best2[e] = -3.4e38f; }

    for (int ph = 0; ph < 8; ++ph) {
        if (ph) __syncthreads();
        int vt0 = ci * 64 + ph * 8;
        int off = vt0 * 64;
        sEH[tid]       = EH[off + tid];
        sEH[tid + 256] = EH[off + tid + 256];
        sEL[tid]       = EL[off + tid];
        sEL[tid + 256] = EL[off + tid + 256];
        if (tid < 128) sen[tid] = enneg[vt0 * 16 + tid];
        __syncthreads();
        __builtin_amdgcn_s_setprio(1);     // T5: favor compute-phase waves
#pragma unroll
        for (int s2 = 0; s2 < 4; ++s2) {
            int s0 = 2 * s2, s1 = s0 + 1;
            bf8 eh0 = sEH[s0 * 64 + lane], el0 = sEL[s0 * 64 + lane];
            bf8 eh1 = sEH[s1 * 64 + lane], el1 = sEL[s1 * 64 + lane];
            float ng0 = sen[s0 * 16 + col], ng1 = sen[s1 * 16 + col];
            unsigned vtb0 = 63u - (unsigned)(ph * 8 + s0);
            unsigned vtb1 = 63u - (unsigned)(ph * 8 + s1);
#pragma unroll
            for (int t = 0; t < 2; ++t) {
                f4 a0 = {ng0, ng0, ng0, ng0};
                a0 = __builtin_amdgcn_mfma_f32_16x16x32_bf16(xh[t], eh0, a0, 0, 0, 0);
                a0 = __builtin_amdgcn_mfma_f32_16x16x32_bf16(xh[t], el0, a0, 0, 0, 0);
                a0 = __builtin_amdgcn_mfma_f32_16x16x32_bf16(xl[t], eh0, a0, 0, 0, 0);
                f4 a1 = {ng1, ng1, ng1, ng1};
                a1 = __builtin_amdgcn_mfma_f32_16x16x32_bf16(xh[t], eh1, a1, 0, 0, 0);
                a1 = __builtin_amdgcn_mfma_f32_16x16x32_bf16(xh[t], el1, a1, 0, 0, 0);
                a1 = __builtin_amdgcn_mfma_f32_16x16x32_bf16(xl[t], eh1, a1, 0, 0, 0);
#pragma unroll
                for (int r = 0; r < 4; ++r) {
                    int e = t * 4 + r;
                    float k0 = packkey(a0[r], vtb0);
                    float k1 = packkey(a1[r], vtb1);
                    float ob = best[e];
                    best2[e] = fmaxf(best2[e], __builtin_amdgcn_fmed3f(ob, k0, k1));
                    best[e]  = fmaxf(fmaxf(ob, k0), k1);
                }
            }
        }
        __builtin_amdgcn_s_setprio(0);
    }

#pragma unroll
    for (int t = 0; t < 2; ++t) {
#pragma unroll
        for (int r = 0; r < 4; ++r) {
            float bb = best[t*4+r], b2 = best2[t*4+r];
            int vtl = 63 - (int)(__float_as_uint(bb) & 63u);
            int ii = (ci * 64 + vtl) * 16 + col;
#pragma unroll
            for (int m = 1; m < 16; m <<= 1) {
                float ob  = __shfl_xor(bb, m);
                float ob2 = __shfl_xor(b2, m);
                int   oi  = __shfl_xor(ii, m);
                b2 = fmaxf(fmaxf(b2, ob2), fminf(bb, ob));
                bool take = (ob > bb) || (ob == bb && oi < ii);
                ii = take ? oi : ii;
                bb = fmaxf(bb, ob);
            }
            if (col == 0) {
                int p = base + t * 16 + kb * 4 + r;
                int o = ci * NPTS + p;
                bvv[o] = bb; b2a[o] = b2; iva[o] = ii;
            }
        }
    }
}

// ---- merge 4 splits, write idx, flag ambiguous ----
__global__ void k_merge(const float* __restrict__ bvv, const float* __restrict__ b2a,
                        const int* __restrict__ iva, int* __restrict__ idx,
                        int* __restrict__ cnt, int* __restrict__ flags) {
    int n = blockIdx.x * 256 + threadIdx.x;
    float bb = bvv[n], b2 = b2a[n];
    int ii = iva[n];
#pragma unroll
    for (int s = 1; s < NSPLIT; ++s) {
        float ob  = bvv[s * NPTS + n];
        float ob2 = b2a[s * NPTS + n];
        int   oi  = iva[s * NPTS + n];
        b2 = fmaxf(fmaxf(b2, ob2), fminf(bb, ob));
        bool take = (ob > bb) || (ob == bb && oi < ii);
        ii = take ? oi : ii;
        bb = fmaxf(bb, ob);
    }
    idx[n] = ii;
    if (bb - b2 <= MARG) {
        int pos = atomicAdd(cnt, 1);
        flags[pos] = n;
    }
}

// ---- exact fp32 recheck: 1 block/flagged point, 16 codes/thread ----
__global__ __launch_bounds__(256) void k_exact(const float* __restrict__ f,
        const float* __restrict__ emb, const float* __restrict__ enneg,
        const int* __restrict__ cnt, const int* __restrict__ flags,
        int* __restrict__ idx) {
    __shared__ unsigned long long wred[4];
    int nc = cnt[0];
    int tid = threadIdx.x, wv = tid >> 6, lane = tid & 63;
    for (int fi = blockIdx.x; fi < nc; fi += gridDim.x) {
        int n = flags[fi];
        int b = n >> 12, pix = n & 4095;
        float x[C];
#pragma unroll
        for (int c = 0; c < C; ++c) x[c] = f[((size_t)b * C + c) * 4096 + pix];
        unsigned long long bk = ~0ULL;
        for (int v2 = 0; v2 < 16; v2 += 2) {
            float d[2];
#pragma unroll
            for (int u = 0; u < 2; ++u) {
                int code = (v2 + u) * 256 + tid;
                const float4* e4 = (const float4*)(emb + code * C);
                float d0 = -enneg[code], d1 = 0.f;
#pragma unroll
                for (int j = 0; j < 4; ++j) {
                    float4 q = e4[j];
                    d0 = fmaf(q.x, -x[4*j+0], d0);
                    d0 = fmaf(q.y, -x[4*j+1], d0);
                    d0 = fmaf(q.z, -x[4*j+2], d0);
                    d0 = fmaf(q.w, -x[4*j+3], d0);
                }
#pragma unroll
                for (int j = 4; j < 8; ++j) {
                    float4 q = e4[j];
                    d1 = fmaf(q.x, -x[4*j+0], d1);
                    d1 = fmaf(q.y, -x[4*j+1], d1);
                    d1 = fmaf(q.z, -x[4*j+2], d1);
                    d1 = fmaf(q.w, -x[4*j+3], d1);
                }
                d[u] = d0 + d1;
            }
#pragma unroll
            for (int u = 0; u < 2; ++u) {
                unsigned long long k = ((unsigned long long)ford(d[u]) << 32)
                                     | (unsigned int)((v2 + u) * 256 + tid);
                bk = k < bk ? k : bk;
            }
        }
#pragma unroll
        for (int m = 1; m < 64; m <<= 1) {
            unsigned long long ok = __shfl_xor(bk, m);
            bk = ok < bk ? ok : bk;
        }
        if (lane == 0) wred[wv] = bk;
        __syncthreads();
        if (tid == 0) {
            unsigned long long k0 = wred[0];
            k0 = wred[1] < k0 ? wred[1] : k0;
            k0 = wred[2] < k0 ? wred[2] : k0;
            k0 = wred[3] < k0 ? wred[3] : k0;
            idx[n] = (int)(k0 & 0xFFFFu);
        }
        __syncthreads();
    }
}

// ---- MFMA conv: 1024 blocks x 256 thr (no fence; separate final reduce) ----
__global__ __launch_bounds__(256) void k_conv(const float* __restrict__ f,
        const float* __restrict__ emb, const unsigned short* __restrict__ EB16,
        const bf8* __restrict__ WB, const int* __restrict__ idx,
        const float* __restrict__ cb, float* __restrict__ out,
        float* __restrict__ partial) {
    __shared__ unsigned short ht[108 * 40];   // bf16 h halo tile [6][18][40] 8.6KB
    __shared__ int sid[108];
    __shared__ float S[64 * 34];              // f_hat stage [pix][oc] 8.7KB
    __shared__ float red[256];

    int blk = blockIdx.x;
    int b = blk >> 6, t = blk & 63;
    int y0 = (t >> 2) * 4, x0 = (t & 3) * 16;
    int tid = threadIdx.x;

    {   // gather 108 halo points, 2 threads/point (32B each)
        int p = tid >> 1, half = tid & 1;
        if (p < 108) {
            int gy = y0 + p / 18 - 1;
            int gx = x0 + p % 18 - 1;
            int4 v0 = {0,0,0,0}, v1 = {0,0,0,0};
            int id = 0;
            if (gy >= 0 && gy < HH && gx >= 0 && gx < WW) {
                id = idx[b * 4096 + gy * WW + gx];
                const int4* e = (const int4*)(EB16 + id * 32 + half * 16);
                v0 = e[0]; v1 = e[1];
            }
            if (half == 0) sid[p] = id;
            int4* dst = (int4*)(ht + p * 40 + half * 16);
            dst[0] = v0; dst[1] = v1;
        }
    }
    __syncthreads();

    int lane = tid & 63;
    int wv = tid >> 6;
    int col = lane & 15;
    int kg = lane >> 4;

    f4 acc0 = {0.f, 0.f, 0.f, 0.f}, acc1 = {0.f, 0.f, 0.f, 0.f};
#pragma unroll
    for (int ky = 0; ky < 3; ++ky)
#pragma unroll
    for (int kx = 0; kx < 3; ++kx) {
        bf8 a = *(const bf8*)(ht + ((wv + ky) * 18 + (col + kx)) * 40 + kg * 8);
        int tap = ky * 3 + kx;
        bf8 w0 = WB[(tap * 2 + 0) * 64 + lane];
        bf8 w1 = WB[(tap * 2 + 1) * 64 + lane];
        acc0 = __builtin_amdgcn_mfma_f32_16x16x32_bf16(a, w0, acc0, 0, 0, 0);
        acc1 = __builtin_amdgcn_mfma_f32_16x16x32_bf16(a, w1, acc1, 0, 0, 0);
    }

    float bias0 = cb[col], bias1 = cb[col + 16];
#pragma unroll
    for (int r = 0; r < 4; ++r) {
        int px = kg * 4 + r;
        int id = sid[(wv + 1) * 18 + (px + 1)];
        float h0 = emb[id * 32 + col];
        float h1 = emb[id * 32 + col + 16];
        S[(wv * 16 + px) * 34 + col]      = 0.5f * h0 + 0.5f * (acc0[r] + bias0);
        S[(wv * 16 + px) * 34 + col + 16] = 0.5f * h1 + 0.5f * (acc1[r] + bias1);
    }
    __syncthreads();

    int oc = tid >> 3, yy = (tid & 7) >> 1, x8 = (tid & 1) * 8;
    size_t rb = ((size_t)(b * C + oc) * HH + y0 + yy) * WW + x0 + x8;
    const float* fr = f + rb;
    float* orow = out + rb;
    float ls = 0.f;
#pragma unroll
    for (int i = 0; i < 8; ++i) {
        float fh = S[(yy * 16 + x8 + i) * 34 + oc];
        orow[i] = fh;
        float e = fh - fr[i];
        ls = fmaf(e, e, ls);
    }

    red[tid] = ls;
    __syncthreads();
    for (int s = 128; s > 0; s >>= 1) {
        if (tid < s) red[tid] += red[tid + s];
        __syncthreads();
    }
    if (tid == 0) partial[blk] = red[0];
}

// ---- final loss reduce (1024 partials) ----
__global__ void k_final(const float* __restrict__ partial, float* __restrict__ out_loss) {
    __shared__ float red[256];
    int tid = threadIdx.x;
    red[tid] = partial[tid] + partial[tid + 256] + partial[tid + 512] + partial[tid + 768];
    __syncthreads();
    for (int s = 128; s > 0; s >>= 1) {
        if (tid < s) red[tid] += red[tid + s];
        __syncthreads();
    }
    if (tid == 0) out_loss[0] = 1.25f * red[0] / 2097152.0f;
}

extern "C" void kernel_launch(void* const* d_in, const int* in_sizes, int n_in,
                              void* d_out, int out_size, void* d_ws, size_t ws_size,
                              hipStream_t stream) {
    const float* f   = (const float*)d_in[0];
    const float* emb = (const float*)d_in[1];
    const float* cw  = (const float*)d_in[2];
    const float* cb  = (const float*)d_in[3];
    float* out = (float*)d_out;

    char* w = (char*)d_ws;
    float* enneg   = (float*)w;                 w += V * 4;
    int*   idx     = (int*)w;                   w += NPTS * 4;
    int*   flags   = (int*)w;                   w += NPTS * 4;
    int*   cnt     = (int*)w;                   w += 256;
    float* partial = (float*)w;                 w += 1024 * 4;
    bf8*   EH      = (bf8*)w;                   w += 256 * 64 * 16;
    bf8*   EL      = (bf8*)w;                   w += 256 * 64 * 16;
    unsigned short* EB16 = (unsigned short*)w;  w += V * 32 * 2;
    bf8*   WB      = (bf8*)w;                   w += 9 * 2 * 64 * 16;
    float* bvv     = (float*)w;                 w += NSPLIT * NPTS * 4;
    float* b2a     = (float*)w;                 w += NSPLIT * NPTS * 4;
    int*   iva     = (int*)w;                   w += NSPLIT * NPTS * 4;

    k_prep<<<402, 64, 0, stream>>>(emb, cw, enneg, EB16, EH, EL, WB, cnt);
    k_argmfma<<<512 * NSPLIT, 256, 0, stream>>>(f, EH, EL, enneg, bvv, b2a, iva);
    k_merge<<<NPTS / 256, 256, 0, stream>>>(bvv, b2a, iva, idx, cnt, flags);
    k_exact<<<1024, 256, 0, stream>>>(f, emb, enneg, cnt, flags, idx);
    k_conv<<<1024, 256, 0, stream>>>(f, emb, EB16, WB, idx, cb, out, partial);
    k_final<<<1, 256, 0, stream>>>(partial, out + 2097152);
}

// Round 17
// 98.864 us; speedup vs baseline: 1.0659x; 1.0659x over previous
//
#include <hip/hip_runtime.h>

#define NPTS 65536
#define V 4096
#define C 32
#define HH 64
#define WW 64
#define NSPLIT 4
#define MARG 2.0e-3f

typedef short bf8 __attribute__((ext_vector_type(8)));   // 8 bf16 in 4 VGPRs
typedef float f4 __attribute__((ext_vector_type(4)));

__device__ inline unsigned int ford(float d) {
    unsigned int b = __float_as_uint(d);
    return (b & 0x80000000u) ? ~b : (b | 0x80000000u);
}
__device__ inline short bf16rne(float x) {
    unsigned u = __float_as_uint(x);
    unsigned hb = (u + 0x7FFFu + ((u >> 16) & 1u)) & 0xFFFF0000u;
    return (short)(hb >> 16);
}
__device__ inline float bf16rne_f(float x, short* s) {
    unsigned u = __float_as_uint(x);
    unsigned hb = (u + 0x7FFFu + ((u >> 16) & 1u)) & 0xFFFF0000u;
    *s = (short)(hb >> 16);
    return __uint_as_float(hb);
}
// pack: (bits(a) & ~63) | vtb  -- compiler emits v_and_or_b32
__device__ inline float packkey(float a, unsigned vtb) {
    return __uint_as_float((__float_as_uint(a) & 0xFFFFFFC0u) | vtb);
}

// ---- fused prep, flat work items, 402 x 64 threads ----
__global__ void k_prep(const float* __restrict__ emb, const float* __restrict__ cw,
                       float* __restrict__ enneg, unsigned short* __restrict__ EB16,
                       bf8* __restrict__ EH, bf8* __restrict__ EL,
                       bf8* __restrict__ WB, int* __restrict__ cnt) {
    int g = blockIdx.x * 64 + threadIdx.x;
    if (g < 16384) {                      // codebook -> bf16 hi/lo fragments
        int vt = g >> 6, lane = g & 63;
        int col = lane & 15, k0 = (lane >> 4) * 8;
        const float* e = emb + (vt * 16 + col) * C + k0;
        bf8 h, l;
#pragma unroll
        for (int j = 0; j < 8; ++j) {
            short hs;
            float hf = bf16rne_f(e[j], &hs);
            h[j] = hs;
            l[j] = bf16rne(e[j] - hf);
        }
        EH[g] = h;
        EL[g] = l;
    } else if (g < 20480) {               // enneg = -0.5*||e||^2
        if (g == 16384) { cnt[0] = 0; cnt[1] = 0; }
        int v = g - 16384;
        const float4* e4 = (const float4*)(emb + v * C);
        float s = 0.f;
#pragma unroll
        for (int j = 0; j < 8; ++j) {
            float4 q = e4[j];
            s += q.x*q.x + q.y*q.y + q.z*q.z + q.w*q.w;
        }
        enneg[v] = -0.5f * s;
    } else if (g < 24576) {               // EB16: codebook rows in bf16
        int v = g - 20480;
        const float* e = emb + v * C;
        union { unsigned short us[32]; int4 q[4]; } u;
#pragma unroll
        for (int j = 0; j < 32; ++j) u.us[j] = (unsigned short)bf16rne(e[j]);
        int4* dst = (int4*)(EB16 + v * 32);
#pragma unroll
        for (int j = 0; j < 4; ++j) dst[j] = u.q[j];
    } else if (g < 25728) {               // WB: conv weights as MFMA B-fragments
        int e = g - 24576;
        int tap = e >> 7, rem = e & 127, half = rem >> 6, lane = rem & 63;
        int oc = half * 16 + (lane & 15), k0 = (lane >> 4) * 8;
        bf8 w;
#pragma unroll
        for (int j = 0; j < 8; ++j)
            w[j] = bf16rne(cw[oc * 288 + (k0 + j) * 9 + tap]);
        WB[e] = w;
    }
}

// ---- MFMA coarse argmin (frozen): 32 pts/wave, 1024 codes/split, 2048 blocks ----
__global__ __launch_bounds__(256, 4) void k_argmfma(const float* __restrict__ f,
        const bf8* __restrict__ EH, const bf8* __restrict__ EL,
        const float* __restrict__ enneg, float* __restrict__ bvv,
        float* __restrict__ b2a, int* __restrict__ iva) {
    __shared__ bf8 sEH[512];
    __shared__ bf8 sEL[512];
    __shared__ float sen[128];

    int tid = threadIdx.x;
    int lane = tid & 63;
    int wv = tid >> 6;
    int ci = blockIdx.x >> 9;
    int pb = blockIdx.x & 511;
    int base = pb * 128 + wv * 32;
    int col = lane & 15, kb = lane >> 4;

    bf8 xh[2], xl[2];
#pragma unroll
    for (int t = 0; t < 2; ++t) {
        int n = base + t * 16 + col;
        int b = n >> 12, pix = n & 4095;
        const float* fp = f + ((size_t)(b * C + kb * 8)) * 4096 + pix;
#pragma unroll
        for (int j = 0; j < 8; ++j) {
            float x = fp[(size_t)j * 4096];
            short hs;
            float hf = bf16rne_f(x, &hs);
            xh[t][j] = hs;
            xl[t][j] = bf16rne(x - hf);
        }
    }

    float best[8], best2[8];
#pragma unroll
    for (int e = 0; e < 8; ++e) { best[e] = -3.4e38f; best2[e] = -3.4e38f; }

    for (int ph = 0; ph < 8; ++ph) {
        if (ph) __syncthreads();
        int vt0 = ci * 64 + ph * 8;
        int off = vt0 * 64;
        sEH[tid]       = EH[off + tid];
        sEH[tid + 256] = EH[off + tid + 256];
        sEL[tid]       = EL[off + tid];
        sEL[tid + 256] = EL[off + tid + 256];
        if (tid < 128) sen[tid] = enneg[vt0 * 16 + tid];
        __syncthreads();
#pragma unroll
        for (int s2 = 0; s2 < 4; ++s2) {
            int s0 = 2 * s2, s1 = s0 + 1;
            bf8 eh0 = sEH[s0 * 64 + lane], el0 = sEL[s0 * 64 + lane];
            bf8 eh1 = sEH[s1 * 64 + lane], el1 = sEL[s1 * 64 + lane];
            float ng0 = sen[s0 * 16 + col], ng1 = sen[s1 * 16 + col];
            unsigned vtb0 = 63u - (unsigned)(ph * 8 + s0);
            unsigned vtb1 = 63u - (unsigned)(ph * 8 + s1);
#pragma unroll
            for (int t = 0; t < 2; ++t) {
                f4 a0 = {ng0, ng0, ng0, ng0};
                a0 = __builtin_amdgcn_mfma_f32_16x16x32_bf16(xh[t], eh0, a0, 0, 0, 0);
                a0 = __builtin_amdgcn_mfma_f32_16x16x32_bf16(xh[t], el0, a0, 0, 0, 0);
                a0 = __builtin_amdgcn_mfma_f32_16x16x32_bf16(xl[t], eh0, a0, 0, 0, 0);
                f4 a1 = {ng1, ng1, ng1, ng1};
                a1 = __builtin_amdgcn_mfma_f32_16x16x32_bf16(xh[t], eh1, a1, 0, 0, 0);
                a1 = __builtin_amdgcn_mfma_f32_16x16x32_bf16(xh[t], el1, a1, 0, 0, 0);
                a1 = __builtin_amdgcn_mfma_f32_16x16x32_bf16(xl[t], eh1, a1, 0, 0, 0);
#pragma unroll
                for (int r = 0; r < 4; ++r) {
                    int e = t * 4 + r;
                    float k0 = packkey(a0[r], vtb0);
                    float k1 = packkey(a1[r], vtb1);
                    float ob = best[e];
                    best2[e] = fmaxf(best2[e], __builtin_amdgcn_fmed3f(ob, k0, k1));
                    best[e]  = fmaxf(fmaxf(ob, k0), k1);
                }
            }
        }
    }

#pragma unroll
    for (int t = 0; t < 2; ++t) {
#pragma unroll
        for (int r = 0; r < 4; ++r) {
            float bb = best[t*4+r], b2 = best2[t*4+r];
            int vtl = 63 - (int)(__float_as_uint(bb) & 63u);
            int ii = (ci * 64 + vtl) * 16 + col;
#pragma unroll
            for (int m = 1; m < 16; m <<= 1) {
                float ob  = __shfl_xor(bb, m);
                float ob2 = __shfl_xor(b2, m);
                int   oi  = __shfl_xor(ii, m);
                b2 = fmaxf(fmaxf(b2, ob2), fminf(bb, ob));
                bool take = (ob > bb) || (ob == bb && oi < ii);
                ii = take ? oi : ii;
                bb = fmaxf(bb, ob);
            }
            if (col == 0) {
                int p = base + t * 16 + kb * 4 + r;
                int o = ci * NPTS + p;
                bvv[o] = bb; b2a[o] = b2; iva[o] = ii;
            }
        }
    }
}

// ---- merge 4 splits, write idx, flag ambiguous ----
__global__ void k_merge(const float* __restrict__ bvv, const float* __restrict__ b2a,
                        const int* __restrict__ iva, int* __restrict__ idx,
                        int* __restrict__ cnt, int* __restrict__ flags) {
    int n = blockIdx.x * 256 + threadIdx.x;
    float bb = bvv[n], b2 = b2a[n];
    int ii = iva[n];
#pragma unroll
    for (int s = 1; s < NSPLIT; ++s) {
        float ob  = bvv[s * NPTS + n];
        float ob2 = b2a[s * NPTS + n];
        int   oi  = iva[s * NPTS + n];
        b2 = fmaxf(fmaxf(b2, ob2), fminf(bb, ob));
        bool take = (ob > bb) || (ob == bb && oi < ii);
        ii = take ? oi : ii;
        bb = fmaxf(bb, ob);
    }
    idx[n] = ii;
    if (bb - b2 <= MARG) {
        int pos = atomicAdd(cnt, 1);
        flags[pos] = n;
    }
}

// ---- exact fp32 recheck: 1 block/flagged point, 16 codes/thread ----
__global__ __launch_bounds__(256) void k_exact(const float* __restrict__ f,
        const float* __restrict__ emb, const float* __restrict__ enneg,
        const int* __restrict__ cnt, const int* __restrict__ flags,
        int* __restrict__ idx) {
    __shared__ unsigned long long wred[4];
    int nc = cnt[0];
    int tid = threadIdx.x, wv = tid >> 6, lane = tid & 63;
    for (int fi = blockIdx.x; fi < nc; fi += gridDim.x) {
        int n = flags[fi];
        int b = n >> 12, pix = n & 4095;
        float x[C];
#pragma unroll
        for (int c = 0; c < C; ++c) x[c] = f[((size_t)b * C + c) * 4096 + pix];
        unsigned long long bk = ~0ULL;
        for (int v2 = 0; v2 < 16; v2 += 2) {
            float d[2];
#pragma unroll
            for (int u = 0; u < 2; ++u) {
                int code = (v2 + u) * 256 + tid;
                const float4* e4 = (const float4*)(emb + code * C);
                float d0 = -enneg[code], d1 = 0.f;
#pragma unroll
                for (int j = 0; j < 4; ++j) {
                    float4 q = e4[j];
                    d0 = fmaf(q.x, -x[4*j+0], d0);
                    d0 = fmaf(q.y, -x[4*j+1], d0);
                    d0 = fmaf(q.z, -x[4*j+2], d0);
                    d0 = fmaf(q.w, -x[4*j+3], d0);
                }
#pragma unroll
                for (int j = 4; j < 8; ++j) {
                    float4 q = e4[j];
                    d1 = fmaf(q.x, -x[4*j+0], d1);
                    d1 = fmaf(q.y, -x[4*j+1], d1);
                    d1 = fmaf(q.z, -x[4*j+2], d1);
                    d1 = fmaf(q.w, -x[4*j+3], d1);
                }
                d[u] = d0 + d1;
            }
#pragma unroll
            for (int u = 0; u < 2; ++u) {
                unsigned long long k = ((unsigned long long)ford(d[u]) << 32)
                                     | (unsigned int)((v2 + u) * 256 + tid);
                bk = k < bk ? k : bk;
            }
        }
#pragma unroll
        for (int m = 1; m < 64; m <<= 1) {
            unsigned long long ok = __shfl_xor(bk, m);
            bk = ok < bk ? ok : bk;
        }
        if (lane == 0) wred[wv] = bk;
        __syncthreads();
        if (tid == 0) {
            unsigned long long k0 = wred[0];
            k0 = wred[1] < k0 ? wred[1] : k0;
            k0 = wred[2] < k0 ? wred[2] : k0;
            k0 = wred[3] < k0 ? wred[3] : k0;
            idx[n] = (int)(k0 & 0xFFFFu);
        }
        __syncthreads();
    }
}

// ---- MFMA conv: 1024 blocks x 256 thr (no fence; separate final reduce) ----
__global__ __launch_bounds__(256) void k_conv(const float* __restrict__ f,
        const float* __restrict__ emb, const unsigned short* __restrict__ EB16,
        const bf8* __restrict__ WB, const int* __restrict__ idx,
        const float* __restrict__ cb, float* __restrict__ out,
        float* __restrict__ partial) {
    __shared__ unsigned short ht[108 * 40];   // bf16 h halo tile [6][18][40] 8.6KB
    __shared__ int sid[108];
    __shared__ float S[64 * 34];              // f_hat stage [pix][oc] 8.7KB
    __shared__ float red[256];

    int blk = blockIdx.x;
    int b = blk >> 6, t = blk & 63;
    int y0 = (t >> 2) * 4, x0 = (t & 3) * 16;
    int tid = threadIdx.x;

    {   // gather 108 halo points, 2 threads/point (32B each)
        int p = tid >> 1, half = tid & 1;
        if (p < 108) {
            int gy = y0 + p / 18 - 1;
            int gx = x0 + p % 18 - 1;
            int4 v0 = {0,0,0,0}, v1 = {0,0,0,0};
            int id = 0;
            if (gy >= 0 && gy < HH && gx >= 0 && gx < WW) {
                id = idx[b * 4096 + gy * WW + gx];
                const int4* e = (const int4*)(EB16 + id * 32 + half * 16);
                v0 = e[0]; v1 = e[1];
            }
            if (half == 0) sid[p] = id;
            int4* dst = (int4*)(ht + p * 40 + half * 16);
            dst[0] = v0; dst[1] = v1;
        }
    }
    __syncthreads();

    int lane = tid & 63;
    int wv = tid >> 6;
    int col = lane & 15;
    int kg = lane >> 4;

    f4 acc0 = {0.f, 0.f, 0.f, 0.f}, acc1 = {0.f, 0.f, 0.f, 0.f};
#pragma unroll
    for (int ky = 0; ky < 3; ++ky)
#pragma unroll
    for (int kx = 0; kx < 3; ++kx) {
        bf8 a = *(const bf8*)(ht + ((wv + ky) * 18 + (col + kx)) * 40 + kg * 8);
        int tap = ky * 3 + kx;
        bf8 w0 = WB[(tap * 2 + 0) * 64 + lane];
        bf8 w1 = WB[(tap * 2 + 1) * 64 + lane];
        acc0 = __builtin_amdgcn_mfma_f32_16x16x32_bf16(a, w0, acc0, 0, 0, 0);
        acc1 = __builtin_amdgcn_mfma_f32_16x16x32_bf16(a, w1, acc1, 0, 0, 0);
    }

    float bias0 = cb[col], bias1 = cb[col + 16];
#pragma unroll
    for (int r = 0; r < 4; ++r) {
        int px = kg * 4 + r;
        int id = sid[(wv + 1) * 18 + (px + 1)];
        float h0 = emb[id * 32 + col];
        float h1 = emb[id * 32 + col + 16];
        S[(wv * 16 + px) * 34 + col]      = 0.5f * h0 + 0.5f * (acc0[r] + bias0);
        S[(wv * 16 + px) * 34 + col + 16] = 0.5f * h1 + 0.5f * (acc1[r] + bias1);
    }
    __syncthreads();

    int oc = tid >> 3, yy = (tid & 7) >> 1, x8 = (tid & 1) * 8;
    size_t rb = ((size_t)(b * C + oc) * HH + y0 + yy) * WW + x0 + x8;
    const float* fr = f + rb;
    float* orow = out + rb;
    float ls = 0.f;
#pragma unroll
    for (int i = 0; i < 8; ++i) {
        float fh = S[(yy * 16 + x8 + i) * 34 + oc];
        orow[i] = fh;
        float e = fh - fr[i];
        ls = fmaf(e, e, ls);
    }

    red[tid] = ls;
    __syncthreads();
    for (int s = 128; s > 0; s >>= 1) {
        if (tid < s) red[tid] += red[tid + s];
        __syncthreads();
    }
    if (tid == 0) partial[blk] = red[0];
}

// ---- final loss reduce (1024 partials) ----
__global__ void k_final(const float* __restrict__ partial, float* __restrict__ out_loss) {
    __shared__ float red[256];
    int tid = threadIdx.x;
    red[tid] = partial[tid] + partial[tid + 256] + partial[tid + 512] + partial[tid + 768];
    __syncthreads();
    for (int s = 128; s > 0; s >>= 1) {
        if (tid < s) red[tid] += red[tid + s];
        __syncthreads();
    }
    if (tid == 0) out_loss[0] = 1.25f * red[0] / 2097152.0f;
}

extern "C" void kernel_launch(void* const* d_in, const int* in_sizes, int n_in,
                              void* d_out, int out_size, void* d_ws, size_t ws_size,
                              hipStream_t stream) {
    const float* f   = (const float*)d_in[0];
    const float* emb = (const float*)d_in[1];
    const float* cw  = (const float*)d_in[2];
    const float* cb  = (const float*)d_in[3];
    float* out = (float*)d_out;

    char* w = (char*)d_ws;
    float* enneg   = (float*)w;                 w += V * 4;
    int*   idx     = (int*)w;                   w += NPTS * 4;
    int*   flags   = (int*)w;                   w += NPTS * 4;
    int*   cnt     = (int*)w;                   w += 256;
    float* partial = (float*)w;                 w += 1024 * 4;
    bf8*   EH      = (bf8*)w;                   w += 256 * 64 * 16;
    bf8*   EL      = (bf8*)w;                   w += 256 * 64 * 16;
    unsigned short* EB16 = (unsigned short*)w;  w += V * 32 * 2;
    bf8*   WB      = (bf8*)w;                   w += 9 * 2 * 64 * 16;
    float* bvv     = (float*)w;                 w += NSPLIT * NPTS * 4;
    float* b2a     = (float*)w;                 w += NSPLIT * NPTS * 4;
    int*   iva     = (int*)w;                   w += NSPLIT * NPTS * 4;

    k_prep<<<402, 64, 0, stream>>>(emb, cw, enneg, EB16, EH, EL, WB, cnt);
    k_argmfma<<<512 * NSPLIT, 256, 0, stream>>>(f, EH, EL, enneg, bvv, b2a, iva);
    k_merge<<<NPTS / 256, 256, 0, stream>>>(bvv, b2a, iva, idx, cnt, flags);
    k_exact<<<1024, 256, 0, stream>>>(f, emb, enneg, cnt, flags, idx);
    k_conv<<<1024, 256, 0, stream>>>(f, emb, EB16, WB, idx, cb, out, partial);
    k_final<<<1, 256, 0, stream>>>(partial, out + 2097152);
}